// Round 7
// baseline (109.910 us; speedup 1.0000x reference)
//
#include <hip/hip_runtime.h>

typedef _Float16 f16;
typedef _Float16 f16x8 __attribute__((ext_vector_type(8)));
typedef float f32x4 __attribute__((ext_vector_type(4)));

#define ZC 32
#define HW 1024
#define TPB 256
#define VCH 256           // codes per LDS chunk (16 KB hi-only)
#define NSLICE 32         // V / VCH code slices
#define DELTA 0.004f      // screen margin: > 2x worst-case |S - S_hihi| (~9.8e-4)

__device__ __forceinline__ unsigned int fkey(float x) {
    unsigned int b = __float_as_uint(x);
    return (b & 0x80000000u) ? ~b : (b | 0x80000000u);
}

// Fused prep:
//  blocks [0, zblocks): normalize z rows (shfl reduce), emit f16-hi MFMA
//    B-fragments (ZFh) + f32 normalized rows (Zn); init packed.
//  blocks [zblocks, ..): normalize codebook rows -> e (f32) + Eh (f16 hi).
__global__ void kprep(const float* __restrict__ z, const float* __restrict__ emb,
                      float* __restrict__ e, f16* __restrict__ Eh,
                      f16x8* __restrict__ ZFh, float* __restrict__ Zn,
                      unsigned long long* __restrict__ packed,
                      int N, int V, int zblocks) {
    const int blk = blockIdx.x;
    if (blk < zblocks) {
        int t = blk * TPB + threadIdx.x;
        int lane = t & 63, zt = t >> 6;
        int n = zt * 16 + (lane & 15);
        int b = n >> 10, hw = n & 1023;
        int kb = (lane >> 4) * 8;
        float x[8];
        float s = 0.f;
#pragma unroll
        for (int j = 0; j < 8; ++j) {
            x[j] = z[((size_t)(b * ZC + kb + j)) * HW + hw];
            s += x[j] * x[j];
        }
        // full row norm: lane-groups {lane^16, lane^32} share row n
        s += __shfl_xor(s, 16);
        s += __shfl_xor(s, 32);
        float inv = 1.0f / fmaxf(sqrtf(s), 1e-12f);
        f16x8 h;
        float4 zn0, zn1;
#pragma unroll
        for (int j = 0; j < 8; ++j) {
            float xn = x[j] * inv;
            h[j] = (f16)xn;
            if (j < 4) ((float*)&zn0)[j] = xn; else ((float*)&zn1)[j - 4] = xn;
        }
        ZFh[t] = h;
        float4* zr = (float4*)(Zn + (size_t)n * ZC + kb);
        zr[0] = zn0; zr[1] = zn1;
        // init packed (zblocks * 64 == N)
        int p0 = blk * 64 + threadIdx.x;
        if (threadIdx.x < 64) packed[p0] = 0ull;
    } else {
        int r = (blk - zblocks) * TPB + threadIdx.x;
        if (r >= V) return;
        const float4* src = reinterpret_cast<const float4*>(emb) + (size_t)r * 8;
        float4 v[8];
        float s = 0.f;
#pragma unroll
        for (int j = 0; j < 8; ++j) {
            v[j] = src[j];
            s += v[j].x * v[j].x + v[j].y * v[j].y + v[j].z * v[j].z + v[j].w * v[j].w;
        }
        float inv = 1.0f / fmaxf(sqrtf(s), 1e-12f);
        float4* dst = reinterpret_cast<float4*>(e) + (size_t)r * 8;
        f16* eh = Eh + (size_t)r * ZC;
#pragma unroll
        for (int j = 0; j < 8; ++j) {
            float t0 = v[j].x * inv, t1 = v[j].y * inv, t2 = v[j].z * inv, t3 = v[j].w * inv;
            float4 o; o.x = t0; o.y = t1; o.z = t2; o.w = t3;
            dst[j] = o;
            eh[4 * j + 0] = (f16)t0; eh[4 * j + 1] = (f16)t1;
            eh[4 * j + 2] = (f16)t2; eh[4 * j + 3] = (f16)t3;
        }
    }
}

// K1: screen. hi*hi GEMM, per-z-row running MAX only (no index).
// ct-loop is ROLLED: rounds 4-6 full-unrolled it (#pragma unroll, 16 iters x
// 4 MFMA straight-line) and the register allocator spilled loop state to
// HBM-backed scratch (87-151 MB FETCH / 162-290 MB WRITE per dispatch).
// Round 3's rolled loop at __launch_bounds__(256,4) had zero scratch.
__global__ __launch_bounds__(TPB, 4) void kscreen(const f16x8* __restrict__ ZFh,
                                                  const uint4* __restrict__ Eh,
                                                  float* __restrict__ partmax,
                                                  int Nn) {
    __shared__ uint4 sEh[VCH * 4];   // 256 rows x 4 16B-chunks, XOR-swizzled
    const int tid = threadIdx.x;
    const int zb = blockIdx.x & 63;
    const int cb = blockIdx.x >> 6;

    {
        const uint4* gh = Eh + (size_t)cb * (VCH * 4);
#pragma unroll
        for (int i = 0; i < 4; ++i) {
            int c = tid + i * TPB;
            int r = c >> 2, q = c & 3;
            sEh[(r << 2) | (q ^ ((r >> 1) & 3))] = gh[c];
        }
    }

    const int lane = tid & 63;
    const int wv = tid >> 6;
    const int zt0 = (zb * 4 + wv) * 4;

    f16x8 Bh[4];
#pragma unroll
    for (int i = 0; i < 4; ++i) Bh[i] = ZFh[(size_t)(zt0 + i) * 64 + lane];
    __syncthreads();

    const int r15 = lane & 15, qq = lane >> 4;
    const int laneA = (r15 << 2) | (qq ^ ((r15 >> 1) & 3));

    float bv[4] = {-1e38f, -1e38f, -1e38f, -1e38f};
    for (int ct = 0; ct < VCH / 16; ++ct) {     // rolled — do NOT unroll
        f16x8 Ah = *(const f16x8*)&sEh[ct * 64 + laneA];
#pragma unroll
        for (int i = 0; i < 4; ++i) {
            f32x4 acc = {0.f, 0.f, 0.f, 0.f};
            acc = __builtin_amdgcn_mfma_f32_16x16x32_f16(Ah, Bh[i], acc, 0, 0, 0);
            bv[i] = fmaxf(bv[i],
                          fmaxf(fmaxf(acc[0], acc[1]), fmaxf(acc[2], acc[3])));
        }
    }

#pragma unroll
    for (int i = 0; i < 4; ++i) {
        float v = bv[i];
        v = fmaxf(v, __shfl_xor(v, 16));
        v = fmaxf(v, __shfl_xor(v, 32));
        if (lane < 16)
            partmax[(size_t)cb * Nn + (zt0 + i) * 16 + r15] = v;
    }
}

// K2: refine. Prologue: reduce the 32 partmax slices (thread tid owns row
// zb*256+tid, coalesced loads), redistribute per-lane thresholds via __shfl.
// Then recompute hi*hi scores (bit-identical MFMA); where a score >= thr,
// compute the exact f32 dot and atomicMax the packed (fkey<<32 | inv-idx) key.
__global__ __launch_bounds__(TPB, 4) void krefine(const f16x8* __restrict__ ZFh,
                                                  const uint4* __restrict__ Eh,
                                                  const float* __restrict__ e,
                                                  const float* __restrict__ Zn,
                                                  const float* __restrict__ partmax,
                                                  unsigned long long* __restrict__ packed,
                                                  int Nn, int Vm1) {
    __shared__ uint4 sEh[VCH * 4];
    const int tid = threadIdx.x;
    const int zb = blockIdx.x & 63;
    const int cb = blockIdx.x >> 6;

    {
        const uint4* gh = Eh + (size_t)cb * (VCH * 4);
#pragma unroll
        for (int i = 0; i < 4; ++i) {
            int c = tid + i * TPB;
            int r = c >> 2, q = c & 3;
            sEh[(r << 2) | (q ^ ((r >> 1) & 3))] = gh[c];
        }
    }

    // per-row final max: thread tid owns row zb*256 + tid
    float red = -1e38f;
    {
        const float* pm = partmax + zb * 256 + tid;
        for (int s = 0; s < NSLICE; ++s) red = fmaxf(red, pm[(size_t)s * Nn]);
    }

    const int lane = tid & 63;
    const int wv = tid >> 6;
    const int zt0 = (zb * 4 + wv) * 4;
    const int r15 = lane & 15, qq = lane >> 4;

    f16x8 Bh[4];
    float thr[4];
#pragma unroll
    for (int i = 0; i < 4; ++i) {
        Bh[i] = ZFh[(size_t)(zt0 + i) * 64 + lane];
        // row wv*64 + i*16 + r15 is held by in-wave lane i*16 + r15
        thr[i] = __shfl(red, i * 16 + r15) - DELTA;
    }
    __syncthreads();

    const int laneA = (r15 << 2) | (qq ^ ((r15 >> 1) & 3));

    for (int ct = 0; ct < VCH / 16; ++ct) {     // rolled — do NOT unroll
        f16x8 Ah = *(const f16x8*)&sEh[ct * 64 + laneA];
#pragma unroll
        for (int i = 0; i < 4; ++i) {
            f32x4 acc = {0.f, 0.f, 0.f, 0.f};
            acc = __builtin_amdgcn_mfma_f32_16x16x32_f16(Ah, Bh[i], acc, 0, 0, 0);
            float t4 = fmaxf(fmaxf(acc[0], acc[1]), fmaxf(acc[2], acc[3]));
            if (__any(t4 >= thr[i])) {
#pragma unroll
                for (int r = 0; r < 4; ++r) {
                    if (acc[r] >= thr[i]) {
                        int code = cb * VCH + ct * 16 + qq * 4 + r;
                        int row = (zt0 + i) * 16 + r15;
                        const float4* er = (const float4*)e + (size_t)code * 8;
                        const float4* zr = (const float4*)Zn + (size_t)row * 8;
                        float s = 0.f;
#pragma unroll
                        for (int q = 0; q < 8; ++q) {
                            float4 a = er[q], b = zr[q];
                            s = fmaf(a.x, b.x, s); s = fmaf(a.y, b.y, s);
                            s = fmaf(a.z, b.z, s); s = fmaf(a.w, b.w, s);
                        }
                        unsigned long long key =
                            ((unsigned long long)fkey(s) << 32) |
                            (unsigned int)(Vm1 - code);
                        atomicMax(&packed[row], key);
                    }
                }
            }
        }
    }
}

// Final: decode idx, gather normalized code, write z_q (b,c,h,w), partial loss per block.
__global__ void kfinal(const float* __restrict__ Zn, const float* __restrict__ e,
                       const unsigned long long* __restrict__ packed,
                       float* __restrict__ out, float* __restrict__ partial, int V) {
    __shared__ float red[TPB];
    int n = blockIdx.x * TPB + threadIdx.x;
    int b = n >> 10, hw = n & 1023;
    unsigned long long p = packed[n];
    int idx = (V - 1) - (int)(unsigned int)(p & 0xFFFFFFFFull);

    const float4* er = reinterpret_cast<const float4*>(e) + (size_t)idx * 8;
    const float4* zr = reinterpret_cast<const float4*>(Zn) + (size_t)n * 8;
    float loss = 0.f;
#pragma unroll
    for (int q = 0; q < 8; ++q) {
        float4 ev = er[q];
        float4 zv = zr[q];
        float d0 = ev.x - zv.x, d1 = ev.y - zv.y;
        float d2 = ev.z - zv.z, d3 = ev.w - zv.w;
        loss += d0 * d0 + d1 * d1 + d2 * d2 + d3 * d3;
        out[((size_t)b * ZC + (4 * q + 0)) * HW + hw] = ev.x;
        out[((size_t)b * ZC + (4 * q + 1)) * HW + hw] = ev.y;
        out[((size_t)b * ZC + (4 * q + 2)) * HW + hw] = ev.z;
        out[((size_t)b * ZC + (4 * q + 3)) * HW + hw] = ev.w;
    }

    red[threadIdx.x] = loss;
    __syncthreads();
    for (int st = TPB / 2; st > 0; st >>= 1) {
        if (threadIdx.x < st) red[threadIdx.x] += red[threadIdx.x + st];
        __syncthreads();
    }
    if (threadIdx.x == 0) partial[blockIdx.x] = red[0];
}

__global__ void kloss(const float* __restrict__ partial, float* __restrict__ out,
                      int nblocks, int NC) {
    int lane = threadIdx.x;
    float s = (lane < nblocks) ? partial[lane] : 0.f;
#pragma unroll
    for (int off = 32; off > 0; off >>= 1) s += __shfl_down(s, off);
    if (lane == 0) {
        float mean = s / (float)NC;
        out[NC] = mean;             // vq_loss
        out[NC + 1] = 0.25f * mean; // commit_loss (BETA = 0.25)
    }
}

extern "C" void kernel_launch(void* const* d_in, const int* in_sizes, int n_in,
                              void* d_out, int out_size, void* d_ws, size_t ws_size,
                              hipStream_t stream) {
    const float* z = (const float*)d_in[0];
    const float* emb = (const float*)d_in[1];
    float* out = (float*)d_out;

    const int N = in_sizes[0] / ZC;   // 16384
    const int V = in_sizes[1] / ZC;   // 8192

    // workspace layout (16B-aligned)
    char* ws = (char*)d_ws;
    float* e = (float*)ws;                                    // 1 MB
    f16* Eh = (f16*)(ws + (size_t)V * ZC * 4);                // 0.5 MB
    f16x8* ZFh = (f16x8*)(ws + (size_t)V * ZC * 6);           // 1 MB (N*4 frags)
    float* Zn = (float*)(ws + (size_t)V * ZC * 6 + (size_t)N * ZC * 2);   // 2 MB
    float* partmax =
        (float*)(ws + (size_t)V * ZC * 6 + (size_t)N * ZC * 6);           // 2 MB
    unsigned long long* packed =
        (unsigned long long*)((char*)partmax + (size_t)NSLICE * N * 4);   // 128 KB
    float* partial = (float*)((char*)packed + (size_t)N * 8);

    const int zblocks = (N * 4 + TPB - 1) / TPB;   // 256
    const int eblocks = (V + TPB - 1) / TPB;       // 32
    const int grid = (V / VCH) * (N / 256);        // 32 * 64 = 2048

    kprep<<<zblocks + eblocks, TPB, 0, stream>>>(z, emb, e, Eh, ZFh, Zn,
                                                 packed, N, V, zblocks);
    kscreen<<<grid, TPB, 0, stream>>>(ZFh, (const uint4*)Eh, partmax, N);
    krefine<<<grid, TPB, 0, stream>>>(ZFh, (const uint4*)Eh, e, Zn, partmax,
                                      packed, N, V - 1);
    kfinal<<<N / TPB, TPB, 0, stream>>>(Zn, e, packed, out, partial, V);
    kloss<<<1, 64, 0, stream>>>(partial, out, N / TPB, N * ZC);
}

// Round 8
// 46.033 us; speedup vs baseline: 2.3877x; 2.3877x over previous
//
#include <hip/hip_runtime.h>

typedef _Float16 f16;
typedef _Float16 f16x8 __attribute__((ext_vector_type(8)));
typedef float f32x4 __attribute__((ext_vector_type(4)));

#define ZC 32
#define HW 1024
#define TPB 256
#define VCH 512           // codes per LDS chunk (hi+lo = 64 KB) — round-3 proven
#define ZROWS_BLK 256     // z-rows per block (4 waves x 4 z-tiles x 16)

__device__ __forceinline__ unsigned int fkey(float x) {
    unsigned int b = __float_as_uint(x);
    return (b & 0x80000000u) ? ~b : (b | 0x80000000u);
}

// Fused prep:
//  blocks [0, zblocks): normalize z rows (shfl reduce), emit f16 hi+lo MFMA
//    B-fragments (ZFh/ZFl) + f32 normalized rows (Zn); init packed.
//  blocks [zblocks, ..): normalize codebook rows -> e (f32) + Eh/El (f16 hi/lo).
__global__ void kprep(const float* __restrict__ z, const float* __restrict__ emb,
                      float* __restrict__ e, f16* __restrict__ Eh, f16* __restrict__ El,
                      f16x8* __restrict__ ZFh, f16x8* __restrict__ ZFl,
                      float* __restrict__ Zn,
                      unsigned long long* __restrict__ packed,
                      int N, int V, int zblocks) {
    const int blk = blockIdx.x;
    if (blk < zblocks) {
        int t = blk * TPB + threadIdx.x;
        int lane = t & 63, zt = t >> 6;
        int n = zt * 16 + (lane & 15);
        int b = n >> 10, hw = n & 1023;
        int kb = (lane >> 4) * 8;
        float x[8];
        float s = 0.f;
#pragma unroll
        for (int j = 0; j < 8; ++j) {
            x[j] = z[((size_t)(b * ZC + kb + j)) * HW + hw];
            s += x[j] * x[j];
        }
        // full row norm: lane-groups {lane^16, lane^32} share row n
        s += __shfl_xor(s, 16);
        s += __shfl_xor(s, 32);
        float inv = 1.0f / fmaxf(sqrtf(s), 1e-12f);
        f16x8 h, l;
        float4 zn0, zn1;
#pragma unroll
        for (int j = 0; j < 8; ++j) {
            float xn = x[j] * inv;
            f16 hh = (f16)xn;
            h[j] = hh;
            l[j] = (f16)(xn - (float)hh);
            if (j < 4) ((float*)&zn0)[j] = xn; else ((float*)&zn1)[j - 4] = xn;
        }
        ZFh[t] = h;
        ZFl[t] = l;
        float4* zr = (float4*)(Zn + (size_t)n * ZC + kb);
        zr[0] = zn0; zr[1] = zn1;
        // init packed (zblocks * 64 == N)
        int p0 = blk * 64 + threadIdx.x;
        if (threadIdx.x < 64) packed[p0] = 0ull;
    } else {
        int r = (blk - zblocks) * TPB + threadIdx.x;
        if (r >= V) return;
        const float4* src = reinterpret_cast<const float4*>(emb) + (size_t)r * 8;
        float4 v[8];
        float s = 0.f;
#pragma unroll
        for (int j = 0; j < 8; ++j) {
            v[j] = src[j];
            s += v[j].x * v[j].x + v[j].y * v[j].y + v[j].z * v[j].z + v[j].w * v[j].w;
        }
        float inv = 1.0f / fmaxf(sqrtf(s), 1e-12f);
        float4* dst = reinterpret_cast<float4*>(e) + (size_t)r * 8;
        f16* eh = Eh + (size_t)r * ZC;
        f16* el = El + (size_t)r * ZC;
#pragma unroll
        for (int j = 0; j < 8; ++j) {
            float t0 = v[j].x * inv, t1 = v[j].y * inv, t2 = v[j].z * inv, t3 = v[j].w * inv;
            float4 o; o.x = t0; o.y = t1; o.z = t2; o.w = t3;
            dst[j] = o;
            f16 h0 = (f16)t0, h1 = (f16)t1, h2 = (f16)t2, h3 = (f16)t3;
            eh[4 * j + 0] = h0; eh[4 * j + 1] = h1; eh[4 * j + 2] = h2; eh[4 * j + 3] = h3;
            el[4 * j + 0] = (f16)(t0 - (float)h0);
            el[4 * j + 1] = (f16)(t1 - (float)h1);
            el[4 * j + 2] = (f16)(t2 - (float)h2);
            el[4 * j + 3] = (f16)(t3 - (float)h3);
        }
    }
}

// Main: S^T = E . Z^T via 3-pass f16-split MFMA, fused online argmax per z-row.
// Block: 4 waves x 4 z-tiles = 256 z-rows vs a 512-code LDS chunk (64 KB).
// VERBATIM round-3 structure (42.3 us total, VGPR=108, no traffic anomaly) —
// rounds 4-7's 16KB-LDS screen/refine variants all exhibited ~265 MB/dispatch
// of unexplained HBM traffic regardless of launch-bounds/unroll knobs.
__global__ __launch_bounds__(TPB, 2) void kmfma(const f16x8* __restrict__ ZFh,
                                                const f16x8* __restrict__ ZFl,
                                                const uint4* __restrict__ Eh,
                                                const uint4* __restrict__ El,
                                                unsigned long long* __restrict__ packed,
                                                int Vm1) {
    __shared__ uint4 sEh[VCH * 4];   // 512 rows x 4 16B-chunks, XOR-swizzled
    __shared__ uint4 sEl[VCH * 4];
    const int tid = threadIdx.x;
    const int cb = blockIdx.x & 15;   // code chunk
    const int zb = blockIdx.x >> 4;   // z-row group

    // stage E chunk (hi+lo, 64 KB) with bank-conflict swizzle on the q slot
    {
        const uint4* gh = Eh + (size_t)cb * (VCH * 4);
        const uint4* gl = El + (size_t)cb * (VCH * 4);
#pragma unroll
        for (int i = 0; i < 8; ++i) {
            int c = tid + i * TPB;                 // linear 16B chunk id
            int r = c >> 2, q = c & 3;
            int w = (r << 2) | (q ^ ((r >> 1) & 3));
            sEh[w] = gh[c];
            sEl[w] = gl[c];
        }
    }

    const int lane = tid & 63;
    const int wv = tid >> 6;
    const int zt0 = zb * 16 + wv * 4;

    // B fragments: 4 z-tiles x (hi, lo), fixed for the whole chunk loop
    f16x8 Bh[4], Bl[4];
#pragma unroll
    for (int i = 0; i < 4; ++i) {
        Bh[i] = ZFh[(size_t)(zt0 + i) * 64 + lane];
        Bl[i] = ZFl[(size_t)(zt0 + i) * 64 + lane];
    }
    __syncthreads();

    const int r15 = lane & 15, qq = lane >> 4;
    const int laneA = (r15 << 2) | (qq ^ ((r15 >> 1) & 3));   // swizzled A-read slot

    float bv[4] = {-1e38f, -1e38f, -1e38f, -1e38f};
    int bi[4] = {0, 0, 0, 0};
    int g = cb * VCH + qq * 4;    // code id of acc reg 0 at ct=0

    for (int ct = 0; ct < VCH / 16; ++ct) {
        f16x8 Ah = *(const f16x8*)&sEh[ct * 64 + laneA];
        f16x8 Al = *(const f16x8*)&sEl[ct * 64 + laneA];
#pragma unroll
        for (int i = 0; i < 4; ++i) {
            f32x4 acc = {0.f, 0.f, 0.f, 0.f};
            acc = __builtin_amdgcn_mfma_f32_16x16x32_f16(Ah, Bh[i], acc, 0, 0, 0);
            acc = __builtin_amdgcn_mfma_f32_16x16x32_f16(Ah, Bl[i], acc, 0, 0, 0);
            acc = __builtin_amdgcn_mfma_f32_16x16x32_f16(Al, Bh[i], acc, 0, 0, 0);
#pragma unroll
            for (int r = 0; r < 4; ++r) {
                float v = acc[r];
                bool gt = v > bv[i];
                bi[i] = gt ? (g + r) : bi[i];
                bv[i] = gt ? v : bv[i];
            }
        }
        g += 16;
    }

    // merge the 4 lane-groups holding the same z-row, then one atomic per row
#pragma unroll
    for (int i = 0; i < 4; ++i) {
        unsigned long long key =
            ((unsigned long long)fkey(bv[i]) << 32) | (unsigned int)(Vm1 - bi[i]);
        unsigned long long o;
        o = __shfl_xor(key, 16); if (o > key) key = o;
        o = __shfl_xor(key, 32); if (o > key) key = o;
        if (lane < 16) atomicMax(&packed[(size_t)(zt0 + i) * 16 + r15], key);
    }
}

// Final: decode idx, gather normalized code, write z_q (b,c,h,w), partial loss per block.
__global__ void kfinal(const float* __restrict__ Zn, const float* __restrict__ e,
                       const unsigned long long* __restrict__ packed,
                       float* __restrict__ out, float* __restrict__ partial, int V) {
    __shared__ float red[TPB];
    int n = blockIdx.x * TPB + threadIdx.x;
    int b = n >> 10, hw = n & 1023;
    unsigned long long p = packed[n];
    int idx = (V - 1) - (int)(unsigned int)(p & 0xFFFFFFFFull);

    const float4* er = reinterpret_cast<const float4*>(e) + (size_t)idx * 8;
    const float4* zr = reinterpret_cast<const float4*>(Zn) + (size_t)n * 8;
    float loss = 0.f;
#pragma unroll
    for (int q = 0; q < 8; ++q) {
        float4 ev = er[q];
        float4 zv = zr[q];
        float d0 = ev.x - zv.x, d1 = ev.y - zv.y;
        float d2 = ev.z - zv.z, d3 = ev.w - zv.w;
        loss += d0 * d0 + d1 * d1 + d2 * d2 + d3 * d3;
        out[((size_t)b * ZC + (4 * q + 0)) * HW + hw] = ev.x;
        out[((size_t)b * ZC + (4 * q + 1)) * HW + hw] = ev.y;
        out[((size_t)b * ZC + (4 * q + 2)) * HW + hw] = ev.z;
        out[((size_t)b * ZC + (4 * q + 3)) * HW + hw] = ev.w;
    }

    red[threadIdx.x] = loss;
    __syncthreads();
    for (int st = TPB / 2; st > 0; st >>= 1) {
        if (threadIdx.x < st) red[threadIdx.x] += red[threadIdx.x + st];
        __syncthreads();
    }
    if (threadIdx.x == 0) partial[blockIdx.x] = red[0];
}

// Loss: one-wave shuffle tree over the 64 block partials (deterministic order).
__global__ void kloss(const float* __restrict__ partial, float* __restrict__ out,
                      int nblocks, int NC) {
    int lane = threadIdx.x;
    float s = (lane < nblocks) ? partial[lane] : 0.f;
#pragma unroll
    for (int off = 32; off > 0; off >>= 1) s += __shfl_down(s, off);
    if (lane == 0) {
        float mean = s / (float)NC;
        out[NC] = mean;             // vq_loss
        out[NC + 1] = 0.25f * mean; // commit_loss (BETA = 0.25)
    }
}

extern "C" void kernel_launch(void* const* d_in, const int* in_sizes, int n_in,
                              void* d_out, int out_size, void* d_ws, size_t ws_size,
                              hipStream_t stream) {
    const float* z = (const float*)d_in[0];
    const float* emb = (const float*)d_in[1];
    float* out = (float*)d_out;

    const int N = in_sizes[0] / ZC;   // 16384
    const int V = in_sizes[1] / ZC;   // 8192

    // workspace layout (16B-aligned)
    char* ws = (char*)d_ws;
    float* e = (float*)ws;                                           // 1 MB
    f16* Eh = (f16*)(ws + (size_t)V * ZC * 4);                       // 0.5 MB
    f16* El = (f16*)(ws + (size_t)V * ZC * 6);                       // 0.5 MB
    f16x8* ZFh = (f16x8*)(ws + (size_t)V * ZC * 8);                  // 1 MB
    f16x8* ZFl = (f16x8*)(ws + (size_t)V * ZC * 8 + (size_t)N * ZC * 2);  // 1 MB
    float* Zn = (float*)(ws + (size_t)V * ZC * 8 + (size_t)N * ZC * 4);   // 2 MB
    unsigned long long* packed =
        (unsigned long long*)(ws + (size_t)V * ZC * 8 + (size_t)N * ZC * 8);  // 128 KB
    float* partial = (float*)((char*)packed + (size_t)N * 8);

    const int zblocks = (N * 4 + TPB - 1) / TPB;   // 256
    const int eblocks = (V + TPB - 1) / TPB;       // 32

    kprep<<<zblocks + eblocks, TPB, 0, stream>>>(z, emb, e, Eh, El, ZFh, ZFl,
                                                 Zn, packed, N, V, zblocks);
    kmfma<<<(V / VCH) * (N / ZROWS_BLK), TPB, 0, stream>>>(
        ZFh, ZFl, (const uint4*)Eh, (const uint4*)El, packed, V - 1);
    kfinal<<<N / TPB, TPB, 0, stream>>>(Zn, e, packed, out, partial, V);
    kloss<<<1, 64, 0, stream>>>(partial, out, N / TPB, N * ZC);
}

// Round 10
// 43.143 us; speedup vs baseline: 2.5476x; 1.0670x over previous
//
#include <hip/hip_runtime.h>

typedef _Float16 f16;
typedef _Float16 f16x8 __attribute__((ext_vector_type(8)));
typedef float f32x4 __attribute__((ext_vector_type(4)));

#define ZC 32
#define HW 1024
#define TPB 256
#define VCH 256           // codes per LDS chunk (hi+lo = 32 KB -> round-3 proven)
#define ZROWS_BLK 256     // z-rows per block (4 waves x 4 z-tiles x 16)

__device__ __forceinline__ unsigned int fkey(float x) {
    unsigned int b = __float_as_uint(x);
    return (b & 0x80000000u) ? ~b : (b | 0x80000000u);
}

// Fused prep:
//  blocks [0, zblocks): normalize z rows (shfl reduce), emit f16 hi+lo MFMA
//    B-fragments (ZFh/ZFl) + f32 normalized rows (Zn); init packed.
//  blocks [zblocks, ..): normalize codebook rows -> e (f32) + Eh/El (f16 hi/lo).
__global__ void kprep(const float* __restrict__ z, const float* __restrict__ emb,
                      float* __restrict__ e, f16* __restrict__ Eh, f16* __restrict__ El,
                      f16x8* __restrict__ ZFh, f16x8* __restrict__ ZFl,
                      float* __restrict__ Zn,
                      unsigned long long* __restrict__ packed,
                      int N, int V, int zblocks) {
    const int blk = blockIdx.x;
    if (blk < zblocks) {
        int t = blk * TPB + threadIdx.x;
        int lane = t & 63, zt = t >> 6;
        int n = zt * 16 + (lane & 15);
        int b = n >> 10, hw = n & 1023;
        int kb = (lane >> 4) * 8;
        float x[8];
        float s = 0.f;
#pragma unroll
        for (int j = 0; j < 8; ++j) {
            x[j] = z[((size_t)(b * ZC + kb + j)) * HW + hw];
            s += x[j] * x[j];
        }
        // full row norm: lane-groups {lane^16, lane^32} share row n
        s += __shfl_xor(s, 16);
        s += __shfl_xor(s, 32);
        float inv = 1.0f / fmaxf(sqrtf(s), 1e-12f);
        f16x8 h, l;
        float4 zn0, zn1;
#pragma unroll
        for (int j = 0; j < 8; ++j) {
            float xn = x[j] * inv;
            f16 hh = (f16)xn;
            h[j] = hh;
            l[j] = (f16)(xn - (float)hh);
            if (j < 4) ((float*)&zn0)[j] = xn; else ((float*)&zn1)[j - 4] = xn;
        }
        ZFh[t] = h;
        ZFl[t] = l;
        float4* zr = (float4*)(Zn + (size_t)n * ZC + kb);
        zr[0] = zn0; zr[1] = zn1;
        // init packed (zblocks * 64 == N)
        int p0 = blk * 64 + threadIdx.x;
        if (threadIdx.x < 64) packed[p0] = 0ull;
    } else {
        int r = (blk - zblocks) * TPB + threadIdx.x;
        if (r >= V) return;
        const float4* src = reinterpret_cast<const float4*>(emb) + (size_t)r * 8;
        float4 v[8];
        float s = 0.f;
#pragma unroll
        for (int j = 0; j < 8; ++j) {
            v[j] = src[j];
            s += v[j].x * v[j].x + v[j].y * v[j].y + v[j].z * v[j].z + v[j].w * v[j].w;
        }
        float inv = 1.0f / fmaxf(sqrtf(s), 1e-12f);
        float4* dst = reinterpret_cast<float4*>(e) + (size_t)r * 8;
        f16* eh = Eh + (size_t)r * ZC;
        f16* el = El + (size_t)r * ZC;
#pragma unroll
        for (int j = 0; j < 8; ++j) {
            float t0 = v[j].x * inv, t1 = v[j].y * inv, t2 = v[j].z * inv, t3 = v[j].w * inv;
            float4 o; o.x = t0; o.y = t1; o.z = t2; o.w = t3;
            dst[j] = o;
            f16 h0 = (f16)t0, h1 = (f16)t1, h2 = (f16)t2, h3 = (f16)t3;
            eh[4 * j + 0] = h0; eh[4 * j + 1] = h1; eh[4 * j + 2] = h2; eh[4 * j + 3] = h3;
            el[4 * j + 0] = (f16)(t0 - (float)h0);
            el[4 * j + 1] = (f16)(t1 - (float)h1);
            el[4 * j + 2] = (f16)(t2 - (float)h2);
            el[4 * j + 3] = (f16)(t3 - (float)h3);
        }
    }
}

// Main: S^T = E . Z^T via 3-pass f16-split MFMA, fused online argmax per z-row.
// Tail per tile: max4 + conditional latch of the 4 acc values (9 VALU vs 12
// for full index select). Index recovered POST-loop from the SAVED values —
// lane-local and bit-exact (round 9's MFMA-recompute recheck was wrong: bct
// is per-lane divergent, and MFMA operands are wave-collective).
__global__ __launch_bounds__(TPB, 4) void kmfma(const f16x8* __restrict__ ZFh,
                                                const f16x8* __restrict__ ZFl,
                                                const uint4* __restrict__ Eh,
                                                const uint4* __restrict__ El,
                                                unsigned long long* __restrict__ packed,
                                                int Vm1) {
    __shared__ uint4 sEh[VCH * 4];   // 256 rows x 4 16B-chunks, XOR-swizzled
    __shared__ uint4 sEl[VCH * 4];
    const int tid = threadIdx.x;
    const int zb = blockIdx.x & 63;   // z-row group (consecutive blocks share cb)
    const int cb = blockIdx.x >> 6;   // code chunk

    // stage E chunk (hi+lo, 32 KB) with bank-conflict swizzle on the q slot
    {
        const uint4* gh = Eh + (size_t)cb * (VCH * 4);
        const uint4* gl = El + (size_t)cb * (VCH * 4);
#pragma unroll
        for (int i = 0; i < 4; ++i) {
            int c = tid + i * TPB;                 // linear 16B chunk id
            int r = c >> 2, q = c & 3;
            int w = (r << 2) | (q ^ ((r >> 1) & 3));
            sEh[w] = gh[c];
            sEl[w] = gl[c];
        }
    }

    const int lane = tid & 63;
    const int wv = tid >> 6;
    const int zt0 = zb * 16 + wv * 4;

    // B fragments: 4 z-tiles x (hi, lo), fixed for the whole chunk loop
    f16x8 Bh[4], Bl[4];
#pragma unroll
    for (int i = 0; i < 4; ++i) {
        Bh[i] = ZFh[(size_t)(zt0 + i) * 64 + lane];
        Bl[i] = ZFl[(size_t)(zt0 + i) * 64 + lane];
    }
    __syncthreads();

    const int r15 = lane & 15, qq = lane >> 4;
    const int laneA = (r15 << 2) | (qq ^ ((r15 >> 1) & 3));   // swizzled A-read slot

    float bv[4] = {-1e38f, -1e38f, -1e38f, -1e38f};
    int bct[4] = {0, 0, 0, 0};
    float sv0[4], sv1[4], sv2[4], sv3[4];
#pragma unroll
    for (int i = 0; i < 4; ++i) { sv0[i] = sv1[i] = sv2[i] = sv3[i] = 0.f; }

    for (int ct = 0; ct < VCH / 16; ++ct) {      // rolled
        f16x8 Ah = *(const f16x8*)&sEh[ct * 64 + laneA];
        f16x8 Al = *(const f16x8*)&sEl[ct * 64 + laneA];
#pragma unroll
        for (int i = 0; i < 4; ++i) {
            f32x4 acc = {0.f, 0.f, 0.f, 0.f};
            acc = __builtin_amdgcn_mfma_f32_16x16x32_f16(Ah, Bh[i], acc, 0, 0, 0);
            acc = __builtin_amdgcn_mfma_f32_16x16x32_f16(Ah, Bl[i], acc, 0, 0, 0);
            acc = __builtin_amdgcn_mfma_f32_16x16x32_f16(Al, Bh[i], acc, 0, 0, 0);
            float t4 = fmaxf(fmaxf(fmaxf(acc[0], acc[1]), acc[2]), acc[3]);
            bool gt = t4 > bv[i];                 // strict: earliest ct wins ties
            bct[i] = gt ? ct : bct[i];
            sv0[i] = gt ? acc[0] : sv0[i];
            sv1[i] = gt ? acc[1] : sv1[i];
            sv2[i] = gt ? acc[2] : sv2[i];
            sv3[i] = gt ? acc[3] : sv3[i];
            bv[i] = gt ? t4 : bv[i];
        }
    }

    // recover element index from the SAVED values (bit-exact, lane-local);
    // first match = lowest code. Then merge lane groups + one atomic per row.
#pragma unroll
    for (int i = 0; i < 4; ++i) {
        int r3 = (sv2[i] == bv[i]) ? 2 : 3;
        int r2 = (sv1[i] == bv[i]) ? 1 : r3;
        int rr = (sv0[i] == bv[i]) ? 0 : r2;
        int idx = cb * VCH + bct[i] * 16 + qq * 4 + rr;

        unsigned long long key =
            ((unsigned long long)fkey(bv[i]) << 32) | (unsigned int)(Vm1 - idx);
        unsigned long long o;
        o = __shfl_xor(key, 16); if (o > key) key = o;
        o = __shfl_xor(key, 32); if (o > key) key = o;
        if (lane < 16) atomicMax(&packed[(size_t)(zt0 + i) * 16 + r15], key);
    }
}

// Final: decode idx, gather normalized code, write z_q (b,c,h,w), partial loss per block.
__global__ void kfinal(const float* __restrict__ Zn, const float* __restrict__ e,
                       const unsigned long long* __restrict__ packed,
                       float* __restrict__ out, float* __restrict__ partial, int V) {
    __shared__ float red[TPB];
    int n = blockIdx.x * TPB + threadIdx.x;
    int b = n >> 10, hw = n & 1023;
    unsigned long long p = packed[n];
    int idx = (V - 1) - (int)(unsigned int)(p & 0xFFFFFFFFull);

    const float4* er = reinterpret_cast<const float4*>(e) + (size_t)idx * 8;
    const float4* zr = reinterpret_cast<const float4*>(Zn) + (size_t)n * 8;
    float loss = 0.f;
#pragma unroll
    for (int q = 0; q < 8; ++q) {
        float4 ev = er[q];
        float4 zv = zr[q];
        float d0 = ev.x - zv.x, d1 = ev.y - zv.y;
        float d2 = ev.z - zv.z, d3 = ev.w - zv.w;
        loss += d0 * d0 + d1 * d1 + d2 * d2 + d3 * d3;
        out[((size_t)b * ZC + (4 * q + 0)) * HW + hw] = ev.x;
        out[((size_t)b * ZC + (4 * q + 1)) * HW + hw] = ev.y;
        out[((size_t)b * ZC + (4 * q + 2)) * HW + hw] = ev.z;
        out[((size_t)b * ZC + (4 * q + 3)) * HW + hw] = ev.w;
    }

    red[threadIdx.x] = loss;
    __syncthreads();
    for (int st = TPB / 2; st > 0; st >>= 1) {
        if (threadIdx.x < st) red[threadIdx.x] += red[threadIdx.x + st];
        __syncthreads();
    }
    if (threadIdx.x == 0) partial[blockIdx.x] = red[0];
}

// Loss: one-wave shuffle tree over the 64 block partials (deterministic order).
__global__ void kloss(const float* __restrict__ partial, float* __restrict__ out,
                      int nblocks, int NC) {
    int lane = threadIdx.x;
    float s = (lane < nblocks) ? partial[lane] : 0.f;
#pragma unroll
    for (int off = 32; off > 0; off >>= 1) s += __shfl_down(s, off);
    if (lane == 0) {
        float mean = s / (float)NC;
        out[NC] = mean;             // vq_loss
        out[NC + 1] = 0.25f * mean; // commit_loss (BETA = 0.25)
    }
}

extern "C" void kernel_launch(void* const* d_in, const int* in_sizes, int n_in,
                              void* d_out, int out_size, void* d_ws, size_t ws_size,
                              hipStream_t stream) {
    const float* z = (const float*)d_in[0];
    const float* emb = (const float*)d_in[1];
    float* out = (float*)d_out;

    const int N = in_sizes[0] / ZC;   // 16384
    const int V = in_sizes[1] / ZC;   // 8192

    // workspace layout (16B-aligned)
    char* ws = (char*)d_ws;
    float* e = (float*)ws;                                           // 1 MB
    f16* Eh = (f16*)(ws + (size_t)V * ZC * 4);                       // 0.5 MB
    f16* El = (f16*)(ws + (size_t)V * ZC * 6);                       // 0.5 MB
    f16x8* ZFh = (f16x8*)(ws + (size_t)V * ZC * 8);                  // 1 MB
    f16x8* ZFl = (f16x8*)(ws + (size_t)V * ZC * 8 + (size_t)N * ZC * 2);  // 1 MB
    float* Zn = (float*)(ws + (size_t)V * ZC * 8 + (size_t)N * ZC * 4);   // 2 MB
    unsigned long long* packed =
        (unsigned long long*)(ws + (size_t)V * ZC * 8 + (size_t)N * ZC * 8);  // 128 KB
    float* partial = (float*)((char*)packed + (size_t)N * 8);

    const int zblocks = (N * 4 + TPB - 1) / TPB;   // 256
    const int eblocks = (V + TPB - 1) / TPB;       // 32

    kprep<<<zblocks + eblocks, TPB, 0, stream>>>(z, emb, e, Eh, El, ZFh, ZFl,
                                                 Zn, packed, N, V, zblocks);
    kmfma<<<(V / VCH) * (N / ZROWS_BLK), TPB, 0, stream>>>(
        ZFh, ZFl, (const uint4*)Eh, (const uint4*)El, packed, V - 1);
    kfinal<<<N / TPB, TPB, 0, stream>>>(Zn, e, packed, out, partial, V);
    kloss<<<1, 64, 0, stream>>>(partial, out, N / TPB, N * ZC);
}